// Round 2
// baseline (208.837 us; speedup 1.0000x reference)
//
#include <hip/hip_runtime.h>

#define S 7
#define NUM_CLASSES 20
#define BATCH 16384
#define NCELLS (BATCH * S * S)        // 802816
#define CPB 128                        // cells per tile
#define NTILES (NCELLS / CPB)          // 6272, exact
#define BLOCK 64                       // ONE wave per block -> no barriers needed
#define GRID 512                       // 2 blocks (2 waves) per CU, persistent
#define TILE_FLOATS (CPB * 30)         // 3840 floats per array per tile (15360 B)
#define GPL 15                         // 16-B granules per lane per array: 960/64

__device__ __forceinline__ void async_load16(const float* g, float* s) {
    // async global -> LDS DMA, 16 B per lane; LDS dst is wave-uniform base +
    // lane*16, which the (it*64 + lane) granule mapping satisfies.
    __builtin_amdgcn_global_load_lds(
        (const __attribute__((address_space(1))) void*)g,
        (__attribute__((address_space(3))) void*)s,
        16, 0, 0);
}

__device__ __forceinline__ float iou_f(float acx, float acy, float aw, float ah,
                                       float bcx, float bcy, float bw, float bh) {
    float ax1 = acx - aw * 0.5f, ay1 = acy - ah * 0.5f;
    float ax2 = acx + aw * 0.5f, ay2 = acy + ah * 0.5f;
    float bx1 = bcx - bw * 0.5f, by1 = bcy - bh * 0.5f;
    float bx2 = bcx + bw * 0.5f, by2 = bcy + bh * 0.5f;
    float iw = fminf(ax2, bx2) - fmaxf(ax1, bx1);
    iw = fmaxf(iw, 0.0f);
    float ih = fminf(ay2, by2) - fmaxf(ay1, by1);
    ih = fmaxf(ih, 0.0f);
    float inter = iw * ih;
    float uni = aw * ah + bw * bh - inter;
    return inter / (uni + 1e-10f);
}

__device__ __forceinline__ float cell_loss(const float* cp, const float* cl) {
    float p[30], l[30];
    const float2* pp = (const float2*)cp;
    const float2* ll = (const float2*)cl;
#pragma unroll
    for (int j = 0; j < 15; ++j) {
        float2 v = pp[j];
        p[2 * j] = v.x; p[2 * j + 1] = v.y;
        float2 w = ll[j];
        l[2 * j] = w.x; l[2 * j + 1] = w.y;
    }

    float obj = (l[4] == 1.0f) ? 1.0f : 0.0f;

    float iou1 = iou_f(p[0], p[1], p[2], p[3], l[0], l[1], l[2], l[3]);
    float iou2 = iou_f(p[5], p[6], p[7], p[8], l[0], l[1], l[2], l[3]);
    bool b1 = iou1 > iou2;

    // labels[5:9] is bitwise-identical to labels[0:4] by construction
    float pxy0 = b1 ? p[0] : p[5];
    float pxy1 = b1 ? p[1] : p[6];
    float pwh0 = b1 ? p[2] : p[7];
    float pwh1 = b1 ? p[3] : p[8];
    float conf_resp  = b1 ? p[4] : p[9];
    float conf_other = b1 ? p[9] : p[4];
    float iou_resp   = b1 ? iou1 : iou2;
    float iou_other  = b1 ? iou2 : iou1;

    float dx = pxy0 - l[0];
    float dy = pxy1 - l[1];
    float loss_xy = dx * dx + dy * dy;

    float sw0 = sqrtf(pwh0) - sqrtf(l[2]);
    float sw1 = sqrtf(pwh1) - sqrtf(l[3]);
    float loss_wh = sw0 * sw0 + sw1 * sw1;

    float d_obj = conf_resp - iou_resp;
    float loss_obj = d_obj * d_obj;

    float d_no = conf_other - iou_other;
    float loss_noobj_in = 0.5f * d_no * d_no;

    float loss_noobj_out = 0.5f * (1.0f - obj) * (p[4] * p[4] + p[9] * p[9]);

    float loss_cls = 0.0f;
#pragma unroll
    for (int c = 10; c < 30; ++c) {
        float d = p[c] - l[c];
        loss_cls += d * d;
    }

    return obj * (5.0f * loss_xy + loss_wh + loss_obj + loss_noobj_in + loss_cls)
         + loss_noobj_out;
}

__global__ __launch_bounds__(BLOCK) void yolo_loss_kernel(
        const float* __restrict__ preds,
        const float* __restrict__ labels,
        float* __restrict__ out) {
    // double-buffered tiles: 2 * 2 * 15360 B = 61440 B -> 2 blocks/CU
    __shared__ __align__(16) float sp[2][TILE_FLOATS];
    __shared__ __align__(16) float sl[2][TILE_FLOATS];

    const int lane = threadIdx.x;     // 0..63, single wave
    float acc = 0.0f;

    // per-lane granule offset (floats), hoisted: f_it = it*1024/4... base lane*4
    const int f0 = lane * 4;          // + it*256 floats per staging step

    int t = blockIdx.x;               // first tile; GRID=512 < NTILES always
    const int iters = (NTILES - (int)blockIdx.x + GRID - 1) / GRID;  // 12 or 13

    // prologue: stage first tile into buffer 0 (30 loads in flight)
    {
        const float* gp = preds  + (size_t)t * TILE_FLOATS;
        const float* gl = labels + (size_t)t * TILE_FLOATS;
#pragma unroll
        for (int it = 0; it < GPL; ++it) {
            int f = f0 + it * 256;
            async_load16(gp + f, &sp[0][f]);
            async_load16(gl + f, &sl[0][f]);
        }
    }

    int bb = 0;
    for (int i = 1; i < iters; ++i) {
        // issue next tile's 30 loads into the other buffer, THEN wait only for
        // the current tile (counted vmcnt — the next tile's loads stay in
        // flight across the compute phase; never drain to 0 mid-loop).
        const int tn = t + GRID;
        const float* gp = preds  + (size_t)tn * TILE_FLOATS;
        const float* gl = labels + (size_t)tn * TILE_FLOATS;
#pragma unroll
        for (int it = 0; it < GPL; ++it) {
            int f = f0 + it * 256;
            async_load16(gp + f, &sp[bb ^ 1][f]);
            async_load16(gl + f, &sl[bb ^ 1][f]);
        }
        asm volatile("s_waitcnt vmcnt(30)" ::: "memory");
        __builtin_amdgcn_sched_barrier(0);   // pin LDS reads after the waitcnt

        // single wave == producer wave: no barrier needed before reading LDS
        acc += cell_loss(&sp[bb][lane * 30],        &sl[bb][lane * 30]);
        acc += cell_loss(&sp[bb][(lane + 64) * 30], &sl[bb][(lane + 64) * 30]);

        t = tn;
        bb ^= 1;
    }

    // epilogue: last tile — nothing left in flight after this wait
    asm volatile("s_waitcnt vmcnt(0)" ::: "memory");
    __builtin_amdgcn_sched_barrier(0);
    acc += cell_loss(&sp[bb][lane * 30],        &sl[bb][lane * 30]);
    acc += cell_loss(&sp[bb][(lane + 64) * 30], &sl[bb][(lane + 64) * 30]);

    // wave-64 shuffle reduction; one atomic per block (512 total)
#pragma unroll
    for (int off = 32; off > 0; off >>= 1)
        acc += __shfl_down(acc, off, 64);
    if (lane == 0)
        atomicAdd(out, acc * (1.0f / (float)BATCH));
}

extern "C" void kernel_launch(void* const* d_in, const int* in_sizes, int n_in,
                              void* d_out, int out_size, void* d_ws, size_t ws_size,
                              hipStream_t stream) {
    const float* preds  = (const float*)d_in[0];
    const float* labels = (const float*)d_in[1];
    float* out = (float*)d_out;

    hipMemsetAsync(out, 0, sizeof(float), stream);  // capture-legal memset node

    yolo_loss_kernel<<<GRID, BLOCK, 0, stream>>>(preds, labels, out);
}